// Round 1
// baseline (384.194 us; speedup 1.0000x reference)
//
#include <hip/hip_runtime.h>
#include <hip/hip_bf16.h>

#define B_ 4
#define L_ 4096
#define D_ 1024
#define H_ 2048
#define M_ (B_*L_)          // 16384 rows
#define NCHUNK 64
#define TCHUNK 64           // NCHUNK*TCHUNK == L_

typedef __attribute__((ext_vector_type(8))) short short8;
typedef __attribute__((ext_vector_type(4))) float floatx4;

__device__ __forceinline__ ushort f2bf(float f){
  uint u = __float_as_uint(f);
  u += 0x7FFFu + ((u >> 16) & 1u);          // RNE
  return (ushort)(u >> 16);
}
__device__ __forceinline__ float bf2f(ushort s){
  return __uint_as_float(((uint)s) << 16);
}

// ---------------- converts ----------------
__global__ void cvt_f32_bf16(const float4* __restrict__ in, ushort4* __restrict__ out, int n4){
  int i = blockIdx.x * blockDim.x + threadIdx.x;
  int stride = gridDim.x * blockDim.x;
  for (; i < n4; i += stride){
    float4 v = in[i];
    ushort4 o;
    o.x = f2bf(v.x); o.y = f2bf(v.y); o.z = f2bf(v.z); o.w = f2bf(v.w);
    out[i] = o;
  }
}

// in [R][C] f32 -> out [C][R] bf16  (R,C multiples of 32)
__global__ void transpose_cvt(const float* __restrict__ in, ushort* __restrict__ out, int R, int C){
  __shared__ float tile[32][33];
  int c0 = blockIdx.x * 32, r0 = blockIdx.y * 32;
  int tx = threadIdx.x, ty = threadIdx.y;   // (32,8)
  #pragma unroll
  for (int i = 0; i < 4; i++){
    int r = r0 + ty + i*8;
    tile[ty + i*8][tx] = in[(size_t)r*C + c0 + tx];
  }
  __syncthreads();
  #pragma unroll
  for (int i = 0; i < 4; i++){
    int c = c0 + ty + i*8;
    out[(size_t)c*R + r0 + tx] = f2bf(tile[tx][ty + i*8]);
  }
}

// ---------------- GEMM1 fused: rz = act(x@Wf, x@Wi) ----------------
// A: xb [M][K=1024] bf16 row-major; B: WfT/WiT [N=2048][K] bf16 (B^T layout)
__global__ __launch_bounds__(256, 2) void gemm1_fused(
    const ushort* __restrict__ xb,
    const ushort* __restrict__ WfT,
    const ushort* __restrict__ WiT,
    const float*  __restrict__ bfv,
    const float*  __restrict__ biv,
    uint*         __restrict__ rz)
{
  constexpr int K = D_;
  constexpr int N = H_;
  __shared__ ushort As [128*64];
  __shared__ ushort Bfs[128*64];
  __shared__ ushort Bis[128*64];

  const int tid  = threadIdx.x;
  const int lane = tid & 63;
  const int wid  = tid >> 6;
  const int wr = wid >> 1, wc = wid & 1;
  const int tm = blockIdx.x * 128;
  const int tn = blockIdx.y * 128;
  const int l15 = lane & 15;
  const int l4  = lane >> 4;

  floatx4 accF[4][4], accI[4][4];
  #pragma unroll
  for (int m = 0; m < 4; m++)
    #pragma unroll
    for (int n = 0; n < 4; n++){ accF[m][n] = (floatx4)(0.f); accI[m][n] = (floatx4)(0.f); }

  for (int k0 = 0; k0 < K; k0 += 64){
    const ushort* Ab = xb  + (size_t)tm*K + k0;
    const ushort* Fb = WfT + (size_t)tn*K + k0;
    const ushort* Ib = WiT + (size_t)tn*K + k0;
    #pragma unroll
    for (int i = 0; i < 4; i++){
      int idx = i*256 + tid;          // 16B chunk id, 1024 chunks = 16KB
      int row = idx >> 3;             // 8 chunks per 64-elem (128B) row
      int ce  = (idx & 7) * 8;        // element offset in row
      __builtin_amdgcn_global_load_lds((const __attribute__((address_space(1))) void*)(Ab + (size_t)row*K + ce),
                                       (__attribute__((address_space(3))) void*)(As + idx*8), 16, 0, 0);
      __builtin_amdgcn_global_load_lds((const __attribute__((address_space(1))) void*)(Fb + (size_t)row*K + ce),
                                       (__attribute__((address_space(3))) void*)(Bfs + idx*8), 16, 0, 0);
      __builtin_amdgcn_global_load_lds((const __attribute__((address_space(1))) void*)(Ib + (size_t)row*K + ce),
                                       (__attribute__((address_space(3))) void*)(Bis + idx*8), 16, 0, 0);
    }
    __syncthreads();
    #pragma unroll
    for (int kk = 0; kk < 64; kk += 32){
      short8 af[4], bff[4], bif[4];
      #pragma unroll
      for (int m = 0; m < 4; m++)
        af[m] = *(const short8*)(As + (wr*64 + m*16 + l15)*64 + kk + l4*8);
      #pragma unroll
      for (int n = 0; n < 4; n++){
        bff[n] = *(const short8*)(Bfs + (wc*64 + n*16 + l15)*64 + kk + l4*8);
        bif[n] = *(const short8*)(Bis + (wc*64 + n*16 + l15)*64 + kk + l4*8);
      }
      #pragma unroll
      for (int m = 0; m < 4; m++)
        #pragma unroll
        for (int n = 0; n < 4; n++){
          accF[m][n] = __builtin_amdgcn_mfma_f32_16x16x32_bf16(af[m], bff[n], accF[m][n], 0, 0, 0);
          accI[m][n] = __builtin_amdgcn_mfma_f32_16x16x32_bf16(af[m], bif[n], accI[m][n], 0, 0, 0);
        }
    }
    __syncthreads();
  }

  // epilogue: r = sigmoid(pf)*lin, z = r*tanh(pi); pack 2xbf16
  #pragma unroll
  for (int n = 0; n < 4; n++){
    int col = tn + wc*64 + n*16 + l15;
    float bfc = bfv[col], bic = biv[col];
    float lin = (float)col * (1.0f / (float)(H_-1));
    #pragma unroll
    for (int m = 0; m < 4; m++){
      int row0 = tm + wr*64 + m*16 + l4*4;
      #pragma unroll
      for (int r = 0; r < 4; r++){
        float pf = accF[m][n][r] + bfc;
        float pi = accI[m][n][r] + bic;
        float rem = lin / (1.0f + __expf(-pf));
        float z   = rem * tanhf(pi);
        rz[(size_t)(row0 + r)*N + col] = (uint)f2bf(rem) | ((uint)f2bf(z) << 16);
      }
    }
  }
}

// ---------------- scan ----------------
// h[t] = (1-r[t])*h[t-1] + z[t],  h[-1] = hidden
__global__ void scan_passA(const uint* __restrict__ rz, float* __restrict__ Ac, float* __restrict__ Bc){
  int gidx = blockIdx.x * blockDim.x + threadIdx.x;
  int h = gidx & (H_-1);
  int t2 = gidx >> 11;
  int chunk = t2 & (NCHUNK-1);
  int b = t2 >> 6;
  const uint* p = rz + ((size_t)(b*L_ + chunk*TCHUNK))*H_ + h;
  float A = 1.f, Bv = 0.f;
  #pragma unroll 8
  for (int t = 0; t < TCHUNK; t++){
    uint u = p[(size_t)t*H_];
    float r = bf2f((ushort)(u & 0xFFFFu));
    float z = bf2f((ushort)(u >> 16));
    float a = 1.f - r;
    A *= a;
    Bv = fmaf(a, Bv, z);
  }
  size_t o = ((size_t)(b*NCHUNK + chunk))*H_ + h;
  Ac[o] = A; Bc[o] = Bv;
}

__global__ void scan_passB(const float* __restrict__ Ac, const float* __restrict__ Bc,
                           const float* __restrict__ hidden, float* __restrict__ hst,
                           float* __restrict__ hlast){
  int idx = blockIdx.x * blockDim.x + threadIdx.x;  // B_*H_ threads
  int h = idx & (H_-1);
  int b = idx >> 11;
  float run = hidden[idx];
  for (int c = 0; c < NCHUNK; c++){
    size_t o = ((size_t)(b*NCHUNK + c))*H_ + h;
    hst[o] = run;
    run = fmaf(Ac[o], run, Bc[o]);
  }
  hlast[idx] = run;
}

__global__ void scan_passC(const uint* __restrict__ rz, const float* __restrict__ hst,
                           ushort* __restrict__ hb){
  int gidx = blockIdx.x * blockDim.x + threadIdx.x;
  int h = gidx & (H_-1);
  int t2 = gidx >> 11;
  int chunk = t2 & (NCHUNK-1);
  int b = t2 >> 6;
  float hv = hst[((size_t)(b*NCHUNK + chunk))*H_ + h];
  const uint* p = rz + ((size_t)(b*L_ + chunk*TCHUNK))*H_ + h;
  ushort*   q  = hb + ((size_t)(b*L_ + chunk*TCHUNK))*H_ + h;
  #pragma unroll 8
  for (int t = 0; t < TCHUNK; t++){
    uint u = p[(size_t)t*H_];
    float r = bf2f((ushort)(u & 0xFFFFu));
    float z = bf2f((ushort)(u >> 16));
    hv = fmaf(1.f - r, hv, z);
    q[(size_t)t*H_] = f2bf(hv);
  }
}

// ---------------- GEMM2: y = h @ Wo + bo ----------------
__global__ __launch_bounds__(256, 2) void gemm2_k(
    const ushort* __restrict__ hb,    // [M][K=2048] bf16
    const ushort* __restrict__ WoT,   // [N=1024][K=2048] bf16
    const float*  __restrict__ bov,
    float*        __restrict__ y)
{
  constexpr int K = H_;
  constexpr int N = D_;
  __shared__ ushort As[128*64];
  __shared__ ushort Bs[128*64];

  const int tid  = threadIdx.x;
  const int lane = tid & 63;
  const int wid  = tid >> 6;
  const int wr = wid >> 1, wc = wid & 1;
  const int tm = blockIdx.x * 128;
  const int tn = blockIdx.y * 128;
  const int l15 = lane & 15;
  const int l4  = lane >> 4;

  floatx4 acc[4][4];
  #pragma unroll
  for (int m = 0; m < 4; m++)
    #pragma unroll
    for (int n = 0; n < 4; n++) acc[m][n] = (floatx4)(0.f);

  for (int k0 = 0; k0 < K; k0 += 64){
    const ushort* Ab = hb  + (size_t)tm*K + k0;
    const ushort* Bb = WoT + (size_t)tn*K + k0;
    #pragma unroll
    for (int i = 0; i < 4; i++){
      int idx = i*256 + tid;
      int row = idx >> 3;
      int ce  = (idx & 7) * 8;
      __builtin_amdgcn_global_load_lds((const __attribute__((address_space(1))) void*)(Ab + (size_t)row*K + ce),
                                       (__attribute__((address_space(3))) void*)(As + idx*8), 16, 0, 0);
      __builtin_amdgcn_global_load_lds((const __attribute__((address_space(1))) void*)(Bb + (size_t)row*K + ce),
                                       (__attribute__((address_space(3))) void*)(Bs + idx*8), 16, 0, 0);
    }
    __syncthreads();
    #pragma unroll
    for (int kk = 0; kk < 64; kk += 32){
      short8 af[4], bf_[4];
      #pragma unroll
      for (int m = 0; m < 4; m++)
        af[m] = *(const short8*)(As + (wr*64 + m*16 + l15)*64 + kk + l4*8);
      #pragma unroll
      for (int n = 0; n < 4; n++)
        bf_[n] = *(const short8*)(Bs + (wc*64 + n*16 + l15)*64 + kk + l4*8);
      #pragma unroll
      for (int m = 0; m < 4; m++)
        #pragma unroll
        for (int n = 0; n < 4; n++)
          acc[m][n] = __builtin_amdgcn_mfma_f32_16x16x32_bf16(af[m], bf_[n], acc[m][n], 0, 0, 0);
    }
    __syncthreads();
  }

  #pragma unroll
  for (int n = 0; n < 4; n++){
    int col = tn + wc*64 + n*16 + l15;
    float bv = bov[col];
    #pragma unroll
    for (int m = 0; m < 4; m++){
      int row0 = tm + wr*64 + m*16 + l4*4;
      #pragma unroll
      for (int r = 0; r < 4; r++)
        y[(size_t)(row0 + r)*N + col] = acc[m][n][r] + bv;
    }
  }
}

extern "C" void kernel_launch(void* const* d_in, const int* in_sizes, int n_in,
                              void* d_out, int out_size, void* d_ws, size_t ws_size,
                              hipStream_t stream)
{
  const float* x      = (const float*)d_in[0];
  const float* hidden = (const float*)d_in[1];
  const float* Wf     = (const float*)d_in[2];
  const float* bf     = (const float*)d_in[3];
  const float* Wi     = (const float*)d_in[4];
  const float* bi     = (const float*)d_in[5];
  const float* Wo     = (const float*)d_in[6];
  const float* bo     = (const float*)d_in[7];

  float* y     = (float*)d_out;                 // [M_][D_]
  float* hlast = y + (size_t)M_*D_;             // [B_][H_]

  char* ws = (char*)d_ws;
  ushort* xb  = (ushort*)ws;  ws += (size_t)M_*D_*2;
  ushort* WfT = (ushort*)ws;  ws += (size_t)H_*D_*2;
  ushort* WiT = (ushort*)ws;  ws += (size_t)H_*D_*2;
  ushort* WoT = (ushort*)ws;  ws += (size_t)D_*H_*2;
  uint*   rz  = (uint*)ws;    ws += (size_t)M_*H_*4;
  ushort* hb  = (ushort*)ws;  ws += (size_t)M_*H_*2;
  float*  Ac  = (float*)ws;   ws += (size_t)B_*NCHUNK*H_*4;
  float*  Bc  = (float*)ws;   ws += (size_t)B_*NCHUNK*H_*4;
  float*  hst = (float*)ws;   ws += (size_t)B_*NCHUNK*H_*4;

  cvt_f32_bf16<<<2048, 256, 0, stream>>>((const float4*)x, (ushort4*)xb, (M_*D_)/4);
  transpose_cvt<<<dim3(H_/32, D_/32), dim3(32,8), 0, stream>>>(Wf, WfT, D_, H_);
  transpose_cvt<<<dim3(H_/32, D_/32), dim3(32,8), 0, stream>>>(Wi, WiT, D_, H_);
  transpose_cvt<<<dim3(D_/32, H_/32), dim3(32,8), 0, stream>>>(Wo, WoT, H_, D_);

  gemm1_fused<<<dim3(M_/128, H_/128), 256, 0, stream>>>(xb, WfT, WiT, bf, bi, rz);

  scan_passA<<<B_*NCHUNK*(H_/256), 256, 0, stream>>>(rz, Ac, Bc);
  scan_passB<<<(B_*H_)/256, 256, 0, stream>>>(Ac, Bc, hidden, hst, hlast);
  scan_passC<<<B_*NCHUNK*(H_/256), 256, 0, stream>>>(rz, hst, hb);

  gemm2_k<<<dim3(M_/128, D_/128), 256, 0, stream>>>(hb, WoT, bo, y);
}

// Round 2
// 313.326 us; speedup vs baseline: 1.2262x; 1.2262x over previous
//
#include <hip/hip_runtime.h>
#include <hip/hip_bf16.h>

#define B_ 4
#define L_ 4096
#define D_ 1024
#define H_ 2048
#define M_ (B_*L_)          // 16384 rows
#define NCHUNK 64
#define TCHUNK 64           // NCHUNK*TCHUNK == L_

typedef __attribute__((ext_vector_type(8))) short short8;
typedef __attribute__((ext_vector_type(4))) float floatx4;

__device__ __forceinline__ ushort f2bf(float f){
  uint u = __float_as_uint(f);
  u += 0x7FFFu + ((u >> 16) & 1u);          // RNE
  return (ushort)(u >> 16);
}
__device__ __forceinline__ float bf2f(ushort s){
  return __uint_as_float(((uint)s) << 16);
}

// ---------------- converts ----------------
__global__ void cvt_f32_bf16(const float4* __restrict__ in, ushort4* __restrict__ out, int n4){
  int i = blockIdx.x * blockDim.x + threadIdx.x;
  int stride = gridDim.x * blockDim.x;
  for (; i < n4; i += stride){
    float4 v = in[i];
    ushort4 o;
    o.x = f2bf(v.x); o.y = f2bf(v.y); o.z = f2bf(v.z); o.w = f2bf(v.w);
    out[i] = o;
  }
}

// in [R][C] f32 -> out [orow(C)][R] bf16  (R,C multiples of 32)
// mode 0: orow = c (plain transpose)
// mode 1: orow = 32*(c/16) + (c%16)        (f-slot of 16-col interleave)
// mode 2: orow = 32*(c/16) + 16 + (c%16)   (i-slot)
__global__ void transpose_cvt(const float* __restrict__ in, ushort* __restrict__ out,
                              int R, int C, int mode){
  __shared__ float tile[32][33];
  int c0 = blockIdx.x * 32, r0 = blockIdx.y * 32;
  int tx = threadIdx.x, ty = threadIdx.y;   // (32,8)
  #pragma unroll
  for (int i = 0; i < 4; i++){
    int r = r0 + ty + i*8;
    tile[ty + i*8][tx] = in[(size_t)r*C + c0 + tx];
  }
  __syncthreads();
  #pragma unroll
  for (int i = 0; i < 4; i++){
    int c = c0 + ty + i*8;
    int orow = (mode == 0) ? c : (((c >> 4) << 5) + ((mode == 2) ? 16 : 0) + (c & 15));
    out[(size_t)orow*R + r0 + tx] = f2bf(tile[tx][ty + i*8]);
  }
}

// ---------------- unified GEMM (m97 structure + chunk XOR swizzle) ----------------
// A [M][K] bf16 row-major; Bm [N][K] bf16 (B^T layout)
// EPI 0: out = float* y, y = acc + b0[col]        (N = plain cols)
// EPI 1: out = uint* rz, interleaved f/i cols -> r,z activation, packed bf16x2
template<int K, int N, int EPI>
__global__ __launch_bounds__(256, 4) void gemm_bt(
    const ushort* __restrict__ A,
    const ushort* __restrict__ Bm,
    const float*  __restrict__ b0,
    const float*  __restrict__ b1,
    void*         __restrict__ outp)
{
  __shared__ ushort As[128*64];
  __shared__ ushort Bs[128*64];

  const int tid  = threadIdx.x;
  const int lane = tid & 63;
  const int wid  = tid >> 6;
  const int wr = wid >> 1, wc = wid & 1;
  const int tm = blockIdx.x * 128;
  const int tn = blockIdx.y * 128;
  const int l15 = lane & 15;
  const int l4  = lane >> 4;

  floatx4 acc[4][4];
  #pragma unroll
  for (int m = 0; m < 4; m++)
    #pragma unroll
    for (int n = 0; n < 4; n++) acc[m][n] = (floatx4)(0.f);

  // per-thread staging coords (swizzled global source -> linear LDS dest)
  const int sidx_row[4] = { (0*256+0), 0,0,0 }; // placeholder to keep arrays simple

  for (int k0 = 0; k0 < K; k0 += 64){
    const ushort* Ab = A  + (size_t)tm*K + k0;
    const ushort* Bb = Bm + (size_t)tn*K + k0;
    #pragma unroll
    for (int i = 0; i < 4; i++){
      int idx = i*256 + tid;                    // 16B chunk id, 1024 chunks = 16KB
      int row = idx >> 3;                       // 8 chunks per 128B row
      int ce  = (((idx & 7) ^ (row & 7)) * 8);  // swizzled source element offset
      __builtin_amdgcn_global_load_lds((const __attribute__((address_space(1))) void*)(Ab + (size_t)row*K + ce),
                                       (__attribute__((address_space(3))) void*)(As + idx*8), 16, 0, 0);
      __builtin_amdgcn_global_load_lds((const __attribute__((address_space(1))) void*)(Bb + (size_t)row*K + ce),
                                       (__attribute__((address_space(3))) void*)(Bs + idx*8), 16, 0, 0);
    }
    __syncthreads();
    #pragma unroll
    for (int kk = 0; kk < 64; kk += 32){
      short8 af[4], bf_[4];
      #pragma unroll
      for (int m = 0; m < 4; m++){
        int row = wr*64 + m*16 + l15;
        int c   = (kk >> 3) + l4;               // chunk 0..7
        af[m] = *(const short8*)(As + row*64 + ((c ^ (row & 7)) * 8));
      }
      #pragma unroll
      for (int n = 0; n < 4; n++){
        int row = wc*64 + n*16 + l15;
        int c   = (kk >> 3) + l4;
        bf_[n] = *(const short8*)(Bs + row*64 + ((c ^ (row & 7)) * 8));
      }
      #pragma unroll
      for (int m = 0; m < 4; m++)
        #pragma unroll
        for (int n = 0; n < 4; n++)
          acc[m][n] = __builtin_amdgcn_mfma_f32_16x16x32_bf16(af[m], bf_[n], acc[m][n], 0, 0, 0);
    }
    __syncthreads();
  }

  if (EPI == 0){
    float* y = (float*)outp;
    #pragma unroll
    for (int n = 0; n < 4; n++){
      int col = tn + wc*64 + n*16 + l15;
      float bv = b0[col];
      #pragma unroll
      for (int m = 0; m < 4; m++){
        int row0 = tm + wr*64 + m*16 + l4*4;
        #pragma unroll
        for (int r = 0; r < 4; r++)
          y[(size_t)(row0 + r)*N + col] = acc[m][n][r] + bv;
      }
    }
  } else {
    // interleaved cols: frag n (even) = f-preact, frag n+1 = i-preact, same h set
    uint* rz = (uint*)outp;
    #pragma unroll
    for (int p = 0; p < 2; p++){
      int n = p*2;
      int h = ((tn + wc*64 + n*16) >> 1) + l15;
      float bfc = b0[h], bic = b1[h];
      float lin = (float)h * (1.0f / (float)(H_-1));
      #pragma unroll
      for (int m = 0; m < 4; m++){
        int row0 = tm + wr*64 + m*16 + l4*4;
        #pragma unroll
        for (int r = 0; r < 4; r++){
          float pf = acc[m][n][r]   + bfc;
          float pi = acc[m][n+1][r] + bic;
          float rem = lin / (1.0f + __expf(-pf));
          float z   = rem * tanhf(pi);
          rz[(size_t)(row0 + r)*H_ + h] = (uint)f2bf(rem) | ((uint)f2bf(z) << 16);
        }
      }
    }
  }
}

// ---------------- scan ----------------
// h[t] = (1-r[t])*h[t-1] + z[t],  h[-1] = hidden
__global__ void scan_passA(const uint* __restrict__ rz, float* __restrict__ Ac, float* __restrict__ Bc){
  int gidx = blockIdx.x * blockDim.x + threadIdx.x;
  int h = gidx & (H_-1);
  int t2 = gidx >> 11;
  int chunk = t2 & (NCHUNK-1);
  int b = t2 >> 6;
  const uint* p = rz + ((size_t)(b*L_ + chunk*TCHUNK))*H_ + h;
  float A = 1.f, Bv = 0.f;
  #pragma unroll 8
  for (int t = 0; t < TCHUNK; t++){
    uint u = p[(size_t)t*H_];
    float r = bf2f((ushort)(u & 0xFFFFu));
    float z = bf2f((ushort)(u >> 16));
    float a = 1.f - r;
    A *= a;
    Bv = fmaf(a, Bv, z);
  }
  size_t o = ((size_t)(b*NCHUNK + chunk))*H_ + h;
  Ac[o] = A; Bc[o] = Bv;
}

__global__ void scan_passB(const float* __restrict__ Ac, const float* __restrict__ Bc,
                           const float* __restrict__ hidden, float* __restrict__ hst,
                           float* __restrict__ hlast){
  int idx = blockIdx.x * blockDim.x + threadIdx.x;  // B_*H_ threads
  int h = idx & (H_-1);
  int b = idx >> 11;
  float run = hidden[idx];
  for (int c = 0; c < NCHUNK; c++){
    size_t o = ((size_t)(b*NCHUNK + c))*H_ + h;
    hst[o] = run;
    run = fmaf(Ac[o], run, Bc[o]);
  }
  hlast[idx] = run;
}

__global__ void scan_passC(const uint* __restrict__ rz, const float* __restrict__ hst,
                           ushort* __restrict__ hb){
  int gidx = blockIdx.x * blockDim.x + threadIdx.x;
  int h = gidx & (H_-1);
  int t2 = gidx >> 11;
  int chunk = t2 & (NCHUNK-1);
  int b = t2 >> 6;
  float hv = hst[((size_t)(b*NCHUNK + chunk))*H_ + h];
  const uint* p = rz + ((size_t)(b*L_ + chunk*TCHUNK))*H_ + h;
  ushort*   q  = hb + ((size_t)(b*L_ + chunk*TCHUNK))*H_ + h;
  #pragma unroll 8
  for (int t = 0; t < TCHUNK; t++){
    uint u = p[(size_t)t*H_];
    float r = bf2f((ushort)(u & 0xFFFFu));
    float z = bf2f((ushort)(u >> 16));
    hv = fmaf(1.f - r, hv, z);
    q[(size_t)t*H_] = f2bf(hv);
  }
}

extern "C" void kernel_launch(void* const* d_in, const int* in_sizes, int n_in,
                              void* d_out, int out_size, void* d_ws, size_t ws_size,
                              hipStream_t stream)
{
  const float* x      = (const float*)d_in[0];
  const float* hidden = (const float*)d_in[1];
  const float* Wf     = (const float*)d_in[2];
  const float* bf     = (const float*)d_in[3];
  const float* Wi     = (const float*)d_in[4];
  const float* bi     = (const float*)d_in[5];
  const float* Wo     = (const float*)d_in[6];
  const float* bo     = (const float*)d_in[7];

  float* y     = (float*)d_out;                 // [M_][D_]
  float* hlast = y + (size_t)M_*D_;             // [B_][H_]

  char* ws = (char*)d_ws;
  ushort* xb   = (ushort*)ws;  ws += (size_t)M_*D_*2;
  ushort* WfiT = (ushort*)ws;  ws += (size_t)(2*H_)*D_*2;   // [4096][1024] interleaved
  ushort* WoT  = (ushort*)ws;  ws += (size_t)D_*H_*2;
  uint*   rz   = (uint*)ws;    ws += (size_t)M_*H_*4;
  ushort* hb   = (ushort*)ws;  ws += (size_t)M_*H_*2;
  float*  Ac   = (float*)ws;   ws += (size_t)B_*NCHUNK*H_*4;
  float*  Bc   = (float*)ws;   ws += (size_t)B_*NCHUNK*H_*4;
  float*  hst  = (float*)ws;   ws += (size_t)B_*NCHUNK*H_*4;

  cvt_f32_bf16<<<2048, 256, 0, stream>>>((const float4*)x, (ushort4*)xb, (M_*D_)/4);
  transpose_cvt<<<dim3(H_/32, D_/32), dim3(32,8), 0, stream>>>(Wf, WfiT, D_, H_, 1);
  transpose_cvt<<<dim3(H_/32, D_/32), dim3(32,8), 0, stream>>>(Wi, WfiT, D_, H_, 2);
  transpose_cvt<<<dim3(D_/32, H_/32), dim3(32,8), 0, stream>>>(Wo, WoT, H_, D_, 0);

  // gemm1: [M][1024] @ interleaved [4096][1024]^T -> rz activations
  gemm_bt<D_, 2*H_, 1><<<dim3(M_/128, (2*H_)/128), 256, 0, stream>>>(xb, WfiT, bf, bi, rz);

  scan_passA<<<B_*NCHUNK*(H_/256), 256, 0, stream>>>(rz, Ac, Bc);
  scan_passB<<<(B_*H_)/256, 256, 0, stream>>>(Ac, Bc, hidden, hst, hlast);
  scan_passC<<<B_*NCHUNK*(H_/256), 256, 0, stream>>>(rz, hst, hb);

  // gemm2: y = h @ Wo + bo
  gemm_bt<H_, D_, 0><<<dim3(M_/128, D_/128), 256, 0, stream>>>(hb, WoT, bo, nullptr, y);
}